// Round 6
// baseline (1300.288 us; speedup 1.0000x reference)
//
#include <hip/hip_runtime.h>
#include <hip/hip_bf16.h>

#define N_NODES 100000
#define N_EDGES 1200000
#define DIM 64
#define NBUCK ((N_NODES + 127) / 128)        // 782 buckets of 128 nodes
#define CHUNK 8192
#define NBIN ((N_EDGES + CHUNK - 1) / CHUNK) // 147

static __device__ __forceinline__ unsigned short bf16bits(float f) {
    __hip_bfloat16 h = __float2bfloat16(f);
    return *reinterpret_cast<unsigned short*>(&h);
}
static __device__ __forceinline__ float bf16raw2f(unsigned short s) {
    return __uint_as_float(((unsigned)s) << 16);
}

// ---------- hist: per-node degree + per-bucket edge counts ----------
__global__ __launch_bounds__(256) void hist_kernel(const int* __restrict__ dst,
                                                   int* __restrict__ cnt,
                                                   int* __restrict__ bcnt) {
    __shared__ int lb[NBUCK];
    for (int i = threadIdx.x; i < NBUCK; i += 256) lb[i] = 0;
    __syncthreads();
    const int e0 = blockIdx.x * CHUNK;
    const int e1 = min(e0 + CHUNK, N_EDGES);
    for (int e = e0 + threadIdx.x; e < e1; e += 256) {
        int d = dst[e];
        atomicAdd(&cnt[d], 1);
        atomicAdd(&lb[d >> 7], 1);
    }
    __syncthreads();
    for (int i = threadIdx.x; i < NBUCK; i += 256) {
        int c = lb[i];
        if (c) atomicAdd(&bcnt[i], c);
    }
}

// ---------- exclusive scan of bucket counts (one block) ----------
__global__ __launch_bounds__(1024) void bucket_scan_kernel(const int* __restrict__ bcnt,
                                                           int* __restrict__ boff,
                                                           int* __restrict__ bcur) {
    __shared__ int tmp[1024];
    const int t = threadIdx.x;
    int v = (t < NBUCK) ? bcnt[t] : 0;
    tmp[t] = v;
    __syncthreads();
    for (int ofs = 1; ofs < 1024; ofs <<= 1) {
        int x = (t >= ofs) ? tmp[t - ofs] : 0;
        __syncthreads();
        tmp[t] += x;
        __syncthreads();
    }
    if (t < NBUCK) {
        int ex = tmp[t] - v;
        boff[t] = ex;
        bcur[t] = ex;
    }
}

// ---------- bin: scatter edges to bucket granularity, packed ----------
// pack = (dstLocal << 17) | src   (src < 2^17, dstLocal < 128)
__global__ __launch_bounds__(256) void bin_kernel(const int* __restrict__ src,
                                                  const int* __restrict__ dst,
                                                  int* __restrict__ bcur,
                                                  unsigned* __restrict__ tmp) {
    __shared__ int lcnt[NBUCK];
    __shared__ int lbase[NBUCK];
    const int tid = threadIdx.x;
    for (int i = tid; i < NBUCK; i += 256) lcnt[i] = 0;
    __syncthreads();
    const int e0 = blockIdx.x * CHUNK;
    const int e1 = min(e0 + CHUNK, N_EDGES);
    for (int e = e0 + tid; e < e1; e += 256)
        atomicAdd(&lcnt[dst[e] >> 7], 1);
    __syncthreads();
    for (int i = tid; i < NBUCK; i += 256) {
        int c = lcnt[i];
        lbase[i] = c ? atomicAdd(&bcur[i], c) : 0;
    }
    __syncthreads();
    for (int i = tid; i < NBUCK; i += 256) lcnt[i] = 0;
    __syncthreads();
    for (int e = e0 + tid; e < e1; e += 256) {
        int d = dst[e];
        int b = d >> 7;
        int r = atomicAdd(&lcnt[b], 1);
        tmp[lbase[b] + r] = ((unsigned)(d & 127) << 17) | (unsigned)src[e];
    }
}

// ---------- f32 -> bf16 table conversion ----------
__global__ __launch_bounds__(256) void cvt_bf16_kernel(const float* __restrict__ in,
                                                       unsigned short* __restrict__ out) {
    int i = blockIdx.x * blockDim.x + threadIdx.x;
    const int total = N_NODES * DIM / 4;
    if (i >= total) return;
    float4 v = ((const float4*)in)[i];
    ushort4 p;
    p.x = bf16bits(v.x); p.y = bf16bits(v.y); p.z = bf16bits(v.z); p.w = bf16bits(v.w);
    ((ushort4*)out)[i] = p;
}

// ---------- aggregate: one block per 128-node bucket, LDS accumulator ----------
template <int BF16>
__global__ __launch_bounds__(256) void agg_bucket_kernel(
    const float* __restrict__ hf,
    const unsigned short* __restrict__ hb,
    const unsigned* __restrict__ tmp,
    const int* __restrict__ boff,
    const int* __restrict__ bcnt,
    const int* __restrict__ cnt,
    float* __restrict__ mean) {
    __shared__ float sacc[128 * DIM];   // 32 KB
    const int tid = threadIdx.x;
    const int lane = tid & 63;
    const int wid = tid >> 6;
    for (int i = tid; i < 128 * DIM; i += 256) sacc[i] = 0.0f;
    __syncthreads();

    const int b = blockIdx.x;
    const int start = boff[b];
    const int len = bcnt[b];
    const int per = (len + 3) >> 2;
    int e = start + wid * per;
    const int s1 = min(e + per, start + len);

    for (; e + 4 <= s1; e += 4) {
        unsigned v0 = tmp[e], v1 = tmp[e + 1], v2 = tmp[e + 2], v3 = tmp[e + 3];
        float f0, f1, f2, f3;
        if (BF16) {
            f0 = bf16raw2f(hb[(size_t)(v0 & 0x1FFFFu) * DIM + lane]);
            f1 = bf16raw2f(hb[(size_t)(v1 & 0x1FFFFu) * DIM + lane]);
            f2 = bf16raw2f(hb[(size_t)(v2 & 0x1FFFFu) * DIM + lane]);
            f3 = bf16raw2f(hb[(size_t)(v3 & 0x1FFFFu) * DIM + lane]);
        } else {
            f0 = hf[(size_t)(v0 & 0x1FFFFu) * DIM + lane];
            f1 = hf[(size_t)(v1 & 0x1FFFFu) * DIM + lane];
            f2 = hf[(size_t)(v2 & 0x1FFFFu) * DIM + lane];
            f3 = hf[(size_t)(v3 & 0x1FFFFu) * DIM + lane];
        }
        atomicAdd(&sacc[(v0 >> 17) * DIM + lane], f0);
        atomicAdd(&sacc[(v1 >> 17) * DIM + lane], f1);
        atomicAdd(&sacc[(v2 >> 17) * DIM + lane], f2);
        atomicAdd(&sacc[(v3 >> 17) * DIM + lane], f3);
    }
    for (; e < s1; ++e) {
        unsigned v = tmp[e];
        float f = BF16 ? bf16raw2f(hb[(size_t)(v & 0x1FFFFu) * DIM + lane])
                       : hf[(size_t)(v & 0x1FFFFu) * DIM + lane];
        atomicAdd(&sacc[(v >> 17) * DIM + lane], f);
    }
    __syncthreads();

    const int nodeBase = b * 128;
    for (int r = wid * 32; r < wid * 32 + 32; ++r) {
        int n = nodeBase + r;
        if (n < N_NODES)
            mean[(size_t)n * DIM + lane] = sacc[r * DIM + lane] / fmaxf((float)cnt[n], 1.0f);
    }
}

// ---------- combine: out = act(mean@Wl + h@Wr + b) ----------
// lane = node; wave = 16-wide output slice (j0 wave-uniform -> scalar W loads).
template <int LAYER>
__global__ __launch_bounds__(256) void combine_kernel(
    const float* __restrict__ mean,
    const float* __restrict__ hf,
    const unsigned short* __restrict__ hb,
    const float* __restrict__ Wl,
    const float* __restrict__ Wr,
    const float* __restrict__ bias,
    const float* __restrict__ u1,
    float* __restrict__ outf,
    unsigned short* __restrict__ outb) {
    const int lane = threadIdx.x & 63;
    const int wv = __builtin_amdgcn_readfirstlane((int)(threadIdx.x >> 6));
    const int j0 = wv * 16;
    const int n0 = blockIdx.x * 64 + lane;
    const int n = (n0 < N_NODES) ? n0 : (N_NODES - 1);
    const bool ok = (n0 < N_NODES);

    float acc[16];
#pragma unroll
    for (int j = 0; j < 16; ++j) acc[j] = bias[j0 + j];

    const float* mrow = mean + (size_t)n * DIM;
#pragma unroll
    for (int kc = 0; kc < DIM; kc += 4) {
        float4 am = *(const float4*)(mrow + kc);
        float a4[4] = {am.x, am.y, am.z, am.w};
#pragma unroll
        for (int kk = 0; kk < 4; ++kk) {
#pragma unroll
            for (int j = 0; j < 16; ++j)
                acc[j] += a4[kk] * Wl[(kc + kk) * DIM + j0 + j];
        }
    }

    if (LAYER == 1) {
        const float* hrow = hf + (size_t)n * DIM;
#pragma unroll
        for (int kc = 0; kc < DIM; kc += 4) {
            float4 ah = *(const float4*)(hrow + kc);
            float a4[4] = {ah.x, ah.y, ah.z, ah.w};
#pragma unroll
            for (int kk = 0; kk < 4; ++kk) {
#pragma unroll
                for (int j = 0; j < 16; ++j)
                    acc[j] += a4[kk] * Wr[(kc + kk) * DIM + j0 + j];
            }
        }
    } else {
        const unsigned short* hrow = hb + (size_t)n * DIM;
#pragma unroll
        for (int kc = 0; kc < DIM; kc += 8) {
            union { uint4 q; unsigned short s[8]; } u;
            u.q = *(const uint4*)(hrow + kc);
#pragma unroll
            for (int kk = 0; kk < 8; ++kk) {
                float a = bf16raw2f(u.s[kk]);
#pragma unroll
                for (int j = 0; j < 16; ++j)
                    acc[j] += a * Wr[(kc + kk) * DIM + j0 + j];
            }
        }
    }

#pragma unroll
    for (int j = 0; j < 16; ++j) acc[j] = fmaxf(acc[j], 0.0f);

    if (LAYER == 1) {
        const float* urow = u1 + (size_t)n * DIM + j0;
#pragma unroll
        for (int jc = 0; jc < 16; jc += 4) {
            float4 u4 = *(const float4*)(urow + jc);
            float uv[4] = {u4.x, u4.y, u4.z, u4.w};
#pragma unroll
            for (int t = 0; t < 4; ++t)
                acc[jc + t] = (uv[t] > 0.5f) ? acc[jc + t] * 2.0f : 0.0f;
        }
        if (ok) {
#pragma unroll
            for (int jc = 0; jc < 16; jc += 4) {
                ushort4 p;
                p.x = bf16bits(acc[jc]);
                p.y = bf16bits(acc[jc + 1]);
                p.z = bf16bits(acc[jc + 2]);
                p.w = bf16bits(acc[jc + 3]);
                *(ushort4*)(outb + (size_t)n * DIM + j0 + jc) = p;
            }
        }
    } else {
        if (ok) {
#pragma unroll
            for (int jc = 0; jc < 16; jc += 4) {
                float4 v;
                v.x = acc[jc]; v.y = acc[jc + 1]; v.z = acc[jc + 2]; v.w = acc[jc + 3];
                *(float4*)(outf + (size_t)n * DIM + j0 + jc) = v;
            }
        }
    }
}

extern "C" void kernel_launch(void* const* d_in, const int* in_sizes, int n_in,
                              void* d_out, int out_size, void* d_ws, size_t ws_size,
                              hipStream_t stream) {
    const float* x   = (const float*)d_in[0];
    const int*   ei  = (const int*)d_in[1];
    const float* u1  = (const float*)d_in[2];
    const float* W1l = (const float*)d_in[3];
    const float* W1r = (const float*)d_in[4];
    const float* b1  = (const float*)d_in[5];
    const float* W2l = (const float*)d_in[6];
    const float* W2r = (const float*)d_in[7];
    const float* b2  = (const float*)d_in[8];
    float* out = (float*)d_out;

    const int* src = ei;
    const int* dst = ei + N_EDGES;

    char* ws = (char*)d_ws;
    auto align256 = [](size_t v) { return (v + 255) & ~(size_t)255; };
    size_t o = 0;
    int* cnt  = (int*)(ws + o); o = align256(o + (size_t)N_NODES * 4);
    int* bcnt = (int*)(ws + o); size_t zeroEnd = o + (size_t)NBUCK * 4; o = align256(zeroEnd);
    int* boff = (int*)(ws + o); o = align256(o + (size_t)NBUCK * 4);
    int* bcur = (int*)(ws + o); o = align256(o + (size_t)NBUCK * 4);
    unsigned* tmp = (unsigned*)(ws + o); o = align256(o + (size_t)N_EDGES * 4);
    float* mean = (float*)(ws + o); o = align256(o + (size_t)N_NODES * DIM * 4);
    unsigned short* h1b = (unsigned short*)(ws + o); o = align256(o + (size_t)N_NODES * DIM * 2);
    unsigned short* xb  = (unsigned short*)(ws + o);
    size_t need_xb = o + (size_t)N_NODES * DIM * 2;
    const bool useXb = (ws_size >= need_xb);   // ws_size constant across calls

    hipMemsetAsync(cnt, 0, zeroEnd, stream);   // zeros cnt + bcnt (and gap)

    const int cbBlocks = (N_NODES + 63) / 64;            // 1563
    const int cvBlocks = (N_NODES * DIM / 4 + 255) / 256;

    hist_kernel<<<NBIN, 256, 0, stream>>>(dst, cnt, bcnt);
    bucket_scan_kernel<<<1, 1024, 0, stream>>>(bcnt, boff, bcur);
    bin_kernel<<<NBIN, 256, 0, stream>>>(src, dst, bcur, tmp);

    // ---- Layer 1 ----
    if (useXb) {
        cvt_bf16_kernel<<<cvBlocks, 256, 0, stream>>>(x, xb);
        agg_bucket_kernel<1><<<NBUCK, 256, 0, stream>>>(nullptr, xb, tmp, boff, bcnt, cnt, mean);
    } else {
        agg_bucket_kernel<0><<<NBUCK, 256, 0, stream>>>(x, nullptr, tmp, boff, bcnt, cnt, mean);
    }
    combine_kernel<1><<<cbBlocks, 256, 0, stream>>>(mean, x, nullptr, W1l, W1r, b1, u1,
                                                    nullptr, h1b);

    // ---- Layer 2 ----
    agg_bucket_kernel<1><<<NBUCK, 256, 0, stream>>>(nullptr, h1b, tmp, boff, bcnt, cnt, mean);
    combine_kernel<2><<<cbBlocks, 256, 0, stream>>>(mean, nullptr, h1b, W2l, W2r, b2, nullptr,
                                                    out, nullptr);
}

// Round 7
// 378.184 us; speedup vs baseline: 3.4382x; 3.4382x over previous
//
#include <hip/hip_runtime.h>
#include <hip/hip_bf16.h>

#define N_NODES 100000
#define N_EDGES 1200000
#define DIM 64
#define NBUCK ((N_NODES + 127) / 128)        // 782 buckets of 128 nodes
#define CHUNK 8192
#define NBIN ((N_EDGES + CHUNK - 1) / CHUNK) // 147

static __device__ __forceinline__ unsigned short bf16bits(float f) {
    __hip_bfloat16 h = __float2bfloat16(f);
    return *reinterpret_cast<unsigned short*>(&h);
}
static __device__ __forceinline__ float bf16raw2f(unsigned short s) {
    return __uint_as_float(((unsigned)s) << 16);
}

// ---------- hist: per-node degree + per-bucket edge counts ----------
__global__ __launch_bounds__(256) void hist_kernel(const int* __restrict__ dst,
                                                   int* __restrict__ cnt,
                                                   int* __restrict__ bcnt) {
    __shared__ int lb[NBUCK];
    for (int i = threadIdx.x; i < NBUCK; i += 256) lb[i] = 0;
    __syncthreads();
    const int e0 = blockIdx.x * CHUNK;
    const int e1 = min(e0 + CHUNK, N_EDGES);
    for (int e = e0 + threadIdx.x; e < e1; e += 256) {
        int d = dst[e];
        atomicAdd(&cnt[d], 1);
        atomicAdd(&lb[d >> 7], 1);
    }
    __syncthreads();
    for (int i = threadIdx.x; i < NBUCK; i += 256) {
        int c = lb[i];
        if (c) atomicAdd(&bcnt[i], c);
    }
}

// ---------- exclusive scan of bucket counts (one block) ----------
__global__ __launch_bounds__(1024) void bucket_scan_kernel(const int* __restrict__ bcnt,
                                                           int* __restrict__ boff,
                                                           int* __restrict__ bcur) {
    __shared__ int tmp[1024];
    const int t = threadIdx.x;
    int v = (t < NBUCK) ? bcnt[t] : 0;
    tmp[t] = v;
    __syncthreads();
    for (int ofs = 1; ofs < 1024; ofs <<= 1) {
        int x = (t >= ofs) ? tmp[t - ofs] : 0;
        __syncthreads();
        tmp[t] += x;
        __syncthreads();
    }
    if (t < NBUCK) {
        int ex = tmp[t] - v;
        boff[t] = ex;
        bcur[t] = ex;
    }
}

// ---------- bin: scatter edges to bucket granularity, packed ----------
// pack = (dstLocal << 17) | src   (src < 2^17, dstLocal < 128)
__global__ __launch_bounds__(256) void bin_kernel(const int* __restrict__ src,
                                                  const int* __restrict__ dst,
                                                  int* __restrict__ bcur,
                                                  unsigned* __restrict__ tmp) {
    __shared__ int lcnt[NBUCK];
    __shared__ int lbase[NBUCK];
    const int tid = threadIdx.x;
    for (int i = tid; i < NBUCK; i += 256) lcnt[i] = 0;
    __syncthreads();
    const int e0 = blockIdx.x * CHUNK;
    const int e1 = min(e0 + CHUNK, N_EDGES);
    for (int e = e0 + tid; e < e1; e += 256)
        atomicAdd(&lcnt[dst[e] >> 7], 1);
    __syncthreads();
    for (int i = tid; i < NBUCK; i += 256) {
        int c = lcnt[i];
        lbase[i] = c ? atomicAdd(&bcur[i], c) : 0;
    }
    __syncthreads();
    for (int i = tid; i < NBUCK; i += 256) lcnt[i] = 0;
    __syncthreads();
    for (int e = e0 + tid; e < e1; e += 256) {
        int d = dst[e];
        int b = d >> 7;
        int r = atomicAdd(&lcnt[b], 1);
        tmp[lbase[b] + r] = ((unsigned)(d & 127) << 17) | (unsigned)src[e];
    }
}

// ---------- bucket_sort: full per-node sort within each bucket ----------
// One block per bucket: 128-counter LDS int histogram + scan -> per-node
// start offsets (noff) and node-sorted ssrc, all writes sequential-ish
// within the bucket's ~6KB span.
__global__ __launch_bounds__(256) void bucket_sort_kernel(
    const unsigned* __restrict__ tmp,
    const int* __restrict__ boff,
    const int* __restrict__ bcnt,
    int* __restrict__ noff,
    int* __restrict__ ssrc) {
    __shared__ int lcnt[128];
    __shared__ int lofs[128];
    const int tid = threadIdx.x;
    const int b = blockIdx.x;
    const int start = boff[b];
    const int len = bcnt[b];

    if (tid < 128) lcnt[tid] = 0;
    __syncthreads();
    for (int i = tid; i < len; i += 256)
        atomicAdd(&lcnt[tmp[start + i] >> 17], 1);
    __syncthreads();
    if (tid < 128) lofs[tid] = lcnt[tid];
    __syncthreads();
    for (int ofs = 1; ofs < 128; ofs <<= 1) {
        int v = (tid < 128 && tid >= ofs) ? lofs[tid - ofs] : 0;
        __syncthreads();
        if (tid < 128) lofs[tid] += v;
        __syncthreads();
    }
    // lofs = inclusive scan; exclusive = lofs - lcnt
    if (tid < 128) {
        int ex = lofs[tid] - lcnt[tid];
        int n = b * 128 + tid;
        if (n < N_NODES) noff[n] = start + ex;
        lcnt[tid] = ex;   // becomes the cursor
    }
    __syncthreads();
    for (int i = tid; i < len; i += 256) {
        unsigned v = tmp[start + i];
        int d = v >> 17;
        int r = atomicAdd(&lcnt[d], 1);
        ssrc[start + r] = (int)(v & 0x1FFFFu);
    }
}

// ---------- f32 -> bf16 table conversion ----------
__global__ __launch_bounds__(256) void cvt_bf16_kernel(const float* __restrict__ in,
                                                       unsigned short* __restrict__ out) {
    int i = blockIdx.x * blockDim.x + threadIdx.x;
    const int total = N_NODES * DIM / 4;
    if (i >= total) return;
    float4 v = ((const float4*)in)[i];
    ushort4 p;
    p.x = bf16bits(v.x); p.y = bf16bits(v.y); p.z = bf16bits(v.z); p.w = bf16bits(v.w);
    ((ushort4*)out)[i] = p;
}

// ---------- aggregate: mean over in-neighbors (one wave per node) ----------
__global__ __launch_bounds__(256) void aggregate_f32_kernel(
    const float* __restrict__ h,
    const int* __restrict__ ssrc,
    const int* __restrict__ noff,
    const int* __restrict__ cnt,
    float* __restrict__ mean) {
    const int lane = threadIdx.x & 63;
    const int wave = (blockIdx.x * blockDim.x + threadIdx.x) >> 6;
    if (wave >= N_NODES) return;
    const int n = wave;
    const int start = noff[n];
    const int deg = cnt[n];
    const int end = start + deg;

    float acc = 0.0f;
    for (int base = start; base < end; base += 64) {
        const int m = min(64, end - base);
        int idx = (lane < m) ? ssrc[base + lane] : 0;
        int i = 0;
        for (; i + 8 <= m; i += 8) {
            float v[8];
#pragma unroll
            for (int k = 0; k < 8; ++k) {
                int s = __shfl(idx, i + k, 64);
                v[k] = h[(size_t)s * DIM + lane];
            }
            acc += ((v[0] + v[1]) + (v[2] + v[3])) + ((v[4] + v[5]) + (v[6] + v[7]));
        }
        for (; i < m; ++i) {
            int s = __shfl(idx, i, 64);
            acc += h[(size_t)s * DIM + lane];
        }
    }
    mean[(size_t)n * DIM + lane] = acc / fmaxf((float)deg, 1.0f);
}

__global__ __launch_bounds__(256) void aggregate_bf16_kernel(
    const unsigned short* __restrict__ hb,
    const int* __restrict__ ssrc,
    const int* __restrict__ noff,
    const int* __restrict__ cnt,
    float* __restrict__ mean) {
    const int lane = threadIdx.x & 63;
    const int wave = (blockIdx.x * blockDim.x + threadIdx.x) >> 6;
    if (wave >= N_NODES) return;
    const int n = wave;
    const int start = noff[n];
    const int deg = cnt[n];
    const int end = start + deg;

    float acc = 0.0f;
    for (int base = start; base < end; base += 64) {
        const int m = min(64, end - base);
        int idx = (lane < m) ? ssrc[base + lane] : 0;
        int i = 0;
        for (; i + 8 <= m; i += 8) {
            float v[8];
#pragma unroll
            for (int k = 0; k < 8; ++k) {
                int s = __shfl(idx, i + k, 64);
                v[k] = bf16raw2f(hb[(size_t)s * DIM + lane]);
            }
            acc += ((v[0] + v[1]) + (v[2] + v[3])) + ((v[4] + v[5]) + (v[6] + v[7]));
        }
        for (; i < m; ++i) {
            int s = __shfl(idx, i, 64);
            acc += bf16raw2f(hb[(size_t)s * DIM + lane]);
        }
    }
    mean[(size_t)n * DIM + lane] = acc / fmaxf((float)deg, 1.0f);
}

// ---------- combine: out = act(mean@Wl + h@Wr + b) ----------
// lane = node; wave = 16-wide output slice (j0 wave-uniform -> scalar W loads).
template <int LAYER>
__global__ __launch_bounds__(256) void combine_kernel(
    const float* __restrict__ mean,
    const float* __restrict__ hf,
    const unsigned short* __restrict__ hb,
    const float* __restrict__ Wl,
    const float* __restrict__ Wr,
    const float* __restrict__ bias,
    const float* __restrict__ u1,
    float* __restrict__ outf,
    unsigned short* __restrict__ outb) {
    const int lane = threadIdx.x & 63;
    const int wv = __builtin_amdgcn_readfirstlane((int)(threadIdx.x >> 6));
    const int j0 = wv * 16;
    const int n0 = blockIdx.x * 64 + lane;
    const int n = (n0 < N_NODES) ? n0 : (N_NODES - 1);
    const bool ok = (n0 < N_NODES);

    float acc[16];
#pragma unroll
    for (int j = 0; j < 16; ++j) acc[j] = bias[j0 + j];

    const float* mrow = mean + (size_t)n * DIM;
#pragma unroll
    for (int kc = 0; kc < DIM; kc += 4) {
        float4 am = *(const float4*)(mrow + kc);
        float a4[4] = {am.x, am.y, am.z, am.w};
#pragma unroll
        for (int kk = 0; kk < 4; ++kk) {
#pragma unroll
            for (int j = 0; j < 16; ++j)
                acc[j] += a4[kk] * Wl[(kc + kk) * DIM + j0 + j];
        }
    }

    if (LAYER == 1) {
        const float* hrow = hf + (size_t)n * DIM;
#pragma unroll
        for (int kc = 0; kc < DIM; kc += 4) {
            float4 ah = *(const float4*)(hrow + kc);
            float a4[4] = {ah.x, ah.y, ah.z, ah.w};
#pragma unroll
            for (int kk = 0; kk < 4; ++kk) {
#pragma unroll
                for (int j = 0; j < 16; ++j)
                    acc[j] += a4[kk] * Wr[(kc + kk) * DIM + j0 + j];
            }
        }
    } else {
        const unsigned short* hrow = hb + (size_t)n * DIM;
#pragma unroll
        for (int kc = 0; kc < DIM; kc += 8) {
            union { uint4 q; unsigned short s[8]; } u;
            u.q = *(const uint4*)(hrow + kc);
#pragma unroll
            for (int kk = 0; kk < 8; ++kk) {
                float a = bf16raw2f(u.s[kk]);
#pragma unroll
                for (int j = 0; j < 16; ++j)
                    acc[j] += a * Wr[(kc + kk) * DIM + j0 + j];
            }
        }
    }

#pragma unroll
    for (int j = 0; j < 16; ++j) acc[j] = fmaxf(acc[j], 0.0f);

    if (LAYER == 1) {
        const float* urow = u1 + (size_t)n * DIM + j0;
#pragma unroll
        for (int jc = 0; jc < 16; jc += 4) {
            float4 u4 = *(const float4*)(urow + jc);
            float uv[4] = {u4.x, u4.y, u4.z, u4.w};
#pragma unroll
            for (int t = 0; t < 4; ++t)
                acc[jc + t] = (uv[t] > 0.5f) ? acc[jc + t] * 2.0f : 0.0f;
        }
        if (ok) {
#pragma unroll
            for (int jc = 0; jc < 16; jc += 4) {
                ushort4 p;
                p.x = bf16bits(acc[jc]);
                p.y = bf16bits(acc[jc + 1]);
                p.z = bf16bits(acc[jc + 2]);
                p.w = bf16bits(acc[jc + 3]);
                *(ushort4*)(outb + (size_t)n * DIM + j0 + jc) = p;
            }
        }
    } else {
        if (ok) {
#pragma unroll
            for (int jc = 0; jc < 16; jc += 4) {
                float4 v;
                v.x = acc[jc]; v.y = acc[jc + 1]; v.z = acc[jc + 2]; v.w = acc[jc + 3];
                *(float4*)(outf + (size_t)n * DIM + j0 + jc) = v;
            }
        }
    }
}

extern "C" void kernel_launch(void* const* d_in, const int* in_sizes, int n_in,
                              void* d_out, int out_size, void* d_ws, size_t ws_size,
                              hipStream_t stream) {
    const float* x   = (const float*)d_in[0];
    const int*   ei  = (const int*)d_in[1];
    const float* u1  = (const float*)d_in[2];
    const float* W1l = (const float*)d_in[3];
    const float* W1r = (const float*)d_in[4];
    const float* b1  = (const float*)d_in[5];
    const float* W2l = (const float*)d_in[6];
    const float* W2r = (const float*)d_in[7];
    const float* b2  = (const float*)d_in[8];
    float* out = (float*)d_out;

    const int* src = ei;
    const int* dst = ei + N_EDGES;

    char* ws = (char*)d_ws;
    auto align256 = [](size_t v) { return (v + 255) & ~(size_t)255; };
    size_t o = 0;
    int* cnt  = (int*)(ws + o); o = align256(o + (size_t)N_NODES * 4);
    int* noff = (int*)(ws + o); o = align256(o + (size_t)N_NODES * 4);
    int* bcnt = (int*)(ws + o); size_t zeroEnd = o + (size_t)NBUCK * 4; o = align256(zeroEnd);
    int* boff = (int*)(ws + o); o = align256(o + (size_t)NBUCK * 4);
    int* bcur = (int*)(ws + o); o = align256(o + (size_t)NBUCK * 4);
    int* ssrc = (int*)(ws + o); o = align256(o + (size_t)N_EDGES * 4);
    float* mean = (float*)(ws + o); o = align256(o + (size_t)N_NODES * DIM * 4);
    unsigned* tmp = (unsigned*)mean;   // aliased: tmp fully consumed before mean written
    unsigned short* h1b = (unsigned short*)(ws + o); o = align256(o + (size_t)N_NODES * DIM * 2);
    unsigned short* xb  = (unsigned short*)(ws + o);
    size_t need_xb = o + (size_t)N_NODES * DIM * 2;
    const bool useXb = (ws_size >= need_xb);   // ws_size constant across calls

    // zeroes cnt..bcnt (cnt, noff, bcnt regions — noff is overwritten anyway)
    hipMemsetAsync(cnt, 0, zeroEnd, stream);

    const int cbBlocks = (N_NODES + 63) / 64;            // 1563
    const int cvBlocks = (N_NODES * DIM / 4 + 255) / 256;
    const int aggBlocks = (N_NODES + 3) / 4;             // one wave per node

    hist_kernel<<<NBIN, 256, 0, stream>>>(dst, cnt, bcnt);
    bucket_scan_kernel<<<1, 1024, 0, stream>>>(bcnt, boff, bcur);
    bin_kernel<<<NBIN, 256, 0, stream>>>(src, dst, bcur, tmp);
    bucket_sort_kernel<<<NBUCK, 256, 0, stream>>>(tmp, boff, bcnt, noff, ssrc);

    // ---- Layer 1 ----
    if (useXb) {
        cvt_bf16_kernel<<<cvBlocks, 256, 0, stream>>>(x, xb);
        aggregate_bf16_kernel<<<aggBlocks, 256, 0, stream>>>(xb, ssrc, noff, cnt, mean);
    } else {
        aggregate_f32_kernel<<<aggBlocks, 256, 0, stream>>>(x, ssrc, noff, cnt, mean);
    }
    combine_kernel<1><<<cbBlocks, 256, 0, stream>>>(mean, x, nullptr, W1l, W1r, b1, u1,
                                                    nullptr, h1b);

    // ---- Layer 2 ----
    aggregate_bf16_kernel<<<aggBlocks, 256, 0, stream>>>(h1b, ssrc, noff, cnt, mean);
    combine_kernel<2><<<cbBlocks, 256, 0, stream>>>(mean, nullptr, h1b, W2l, W2r, b2, nullptr,
                                                    out, nullptr);
}

// Round 8
// 323.365 us; speedup vs baseline: 4.0211x; 1.1695x over previous
//
#include <hip/hip_runtime.h>
#include <hip/hip_bf16.h>

#define N_NODES 100000
#define N_EDGES 1200000
#define DIM 64
#define NBUCK ((N_NODES + 127) / 128)           // 782 buckets of 128 nodes
#define HCHUNK 4096
#define NBIN_H ((N_EDGES + HCHUNK - 1) / HCHUNK) // 293
#define BCHUNK 8192
#define NBIN_B ((N_EDGES + BCHUNK - 1) / BCHUNK) // 147

static __device__ __forceinline__ unsigned short bf16bits(float f) {
    __hip_bfloat16 h = __float2bfloat16(f);
    return *reinterpret_cast<unsigned short*>(&h);
}
static __device__ __forceinline__ float bf16raw2f(unsigned short s) {
    return __uint_as_float(((unsigned)s) << 16);
}

// ---------- hist: per-bucket edge counts only (no per-node atomics) ----------
__global__ __launch_bounds__(256) void hist_kernel(const int* __restrict__ dst,
                                                   int* __restrict__ bcnt) {
    __shared__ int lb[NBUCK];
    for (int i = threadIdx.x; i < NBUCK; i += 256) lb[i] = 0;
    __syncthreads();
    const int e0 = blockIdx.x * HCHUNK;
    const int e1 = min(e0 + HCHUNK, N_EDGES);
    for (int e = e0 + threadIdx.x; e < e1; e += 256)
        atomicAdd(&lb[dst[e] >> 7], 1);
    __syncthreads();
    for (int i = threadIdx.x; i < NBUCK; i += 256) {
        int c = lb[i];
        if (c) atomicAdd(&bcnt[i], c);
    }
}

// ---------- exclusive scan of bucket counts (one block) ----------
__global__ __launch_bounds__(1024) void bucket_scan_kernel(const int* __restrict__ bcnt,
                                                           int* __restrict__ boff,
                                                           int* __restrict__ bcur,
                                                           int* __restrict__ noff) {
    __shared__ int tmp[1024];
    const int t = threadIdx.x;
    int v = (t < NBUCK) ? bcnt[t] : 0;
    tmp[t] = v;
    __syncthreads();
    for (int ofs = 1; ofs < 1024; ofs <<= 1) {
        int x = (t >= ofs) ? tmp[t - ofs] : 0;
        __syncthreads();
        tmp[t] += x;
        __syncthreads();
    }
    if (t < NBUCK) {
        int ex = tmp[t] - v;
        boff[t] = ex;
        bcur[t] = ex;
    }
    if (t == 0) noff[N_NODES] = N_EDGES;   // sentinel: deg = noff[n+1]-noff[n]
}

// ---------- bin: scatter edges to bucket granularity, packed ----------
// pack = (dstLocal << 17) | src   (src < 2^17, dstLocal < 128)
__global__ __launch_bounds__(256) void bin_kernel(const int* __restrict__ src,
                                                  const int* __restrict__ dst,
                                                  int* __restrict__ bcur,
                                                  unsigned* __restrict__ tmp) {
    __shared__ int lcnt[NBUCK];
    __shared__ int lbase[NBUCK];
    const int tid = threadIdx.x;
    for (int i = tid; i < NBUCK; i += 256) lcnt[i] = 0;
    __syncthreads();
    const int e0 = blockIdx.x * BCHUNK;
    const int e1 = min(e0 + BCHUNK, N_EDGES);
    for (int e = e0 + tid; e < e1; e += 256)
        atomicAdd(&lcnt[dst[e] >> 7], 1);
    __syncthreads();
    for (int i = tid; i < NBUCK; i += 256) {
        int c = lcnt[i];
        lbase[i] = c ? atomicAdd(&bcur[i], c) : 0;
    }
    __syncthreads();
    for (int i = tid; i < NBUCK; i += 256) lcnt[i] = 0;
    __syncthreads();
    for (int e = e0 + tid; e < e1; e += 256) {
        int d = dst[e];
        int b = d >> 7;
        int r = atomicAdd(&lcnt[b], 1);
        tmp[lbase[b] + r] = ((unsigned)(d & 127) << 17) | (unsigned)src[e];
    }
}

// ---------- bucket_sort: per-node sort within each bucket ----------
__global__ __launch_bounds__(256) void bucket_sort_kernel(
    const unsigned* __restrict__ tmp,
    const int* __restrict__ boff,
    const int* __restrict__ bcnt,
    int* __restrict__ noff,
    int* __restrict__ ssrc) {
    __shared__ int lcnt[128];
    __shared__ int lofs[128];
    const int tid = threadIdx.x;
    const int b = blockIdx.x;
    const int start = boff[b];
    const int len = bcnt[b];

    if (tid < 128) lcnt[tid] = 0;
    __syncthreads();
    for (int i = tid; i < len; i += 256)
        atomicAdd(&lcnt[tmp[start + i] >> 17], 1);
    __syncthreads();
    if (tid < 128) lofs[tid] = lcnt[tid];
    __syncthreads();
    for (int ofs = 1; ofs < 128; ofs <<= 1) {
        int v = (tid < 128 && tid >= ofs) ? lofs[tid - ofs] : 0;
        __syncthreads();
        if (tid < 128) lofs[tid] += v;
        __syncthreads();
    }
    if (tid < 128) {
        int ex = lofs[tid] - lcnt[tid];
        int n = b * 128 + tid;
        if (n < N_NODES) noff[n] = start + ex;
        lcnt[tid] = ex;
    }
    __syncthreads();
    for (int i = tid; i < len; i += 256) {
        unsigned v = tmp[start + i];
        int d = v >> 17;
        int r = atomicAdd(&lcnt[d], 1);
        ssrc[start + r] = (int)(v & 0x1FFFFu);
    }
}

// ---------- f32 -> bf16 table conversion ----------
__global__ __launch_bounds__(256) void cvt_bf16_kernel(const float* __restrict__ in,
                                                       unsigned short* __restrict__ out) {
    int i = blockIdx.x * blockDim.x + threadIdx.x;
    const int total = N_NODES * DIM / 4;
    if (i >= total) return;
    float4 v = ((const float4*)in)[i];
    ushort4 p;
    p.x = bf16bits(v.x); p.y = bf16bits(v.y); p.z = bf16bits(v.z); p.w = bf16bits(v.w);
    ((ushort4*)out)[i] = p;
}

// ---------- aggregate (bf16): 2 edges per wave, 32 lanes each ----------
__global__ __launch_bounds__(256) void aggregate_bf16_kernel(
    const unsigned short* __restrict__ hb,
    const int* __restrict__ ssrc,
    const int* __restrict__ noff,
    float* __restrict__ mean) {
    const int lane = threadIdx.x & 63;
    const int wave = (blockIdx.x * blockDim.x + threadIdx.x) >> 6;
    if (wave >= N_NODES) return;
    const int n = wave;
    const int start = noff[n];
    const int end = noff[n + 1];
    const int deg = end - start;
    const int half = lane >> 5;
    const int fl = lane & 31;

    float acc0 = 0.0f, acc1 = 0.0f;
    for (int base = start; base < end; base += 64) {
        const int m = min(64, end - base);
        int idx = (lane < m) ? ssrc[base + lane] : 0;
        const int npair = m >> 1;
        int i = 0;
        for (; i + 4 <= npair; i += 4) {
            unsigned v[4];
#pragma unroll
            for (int k = 0; k < 4; ++k) {
                int s = __shfl(idx, 2 * (i + k) + half, 64);
                v[k] = *(const unsigned*)(hb + (size_t)s * DIM + fl * 2);
            }
#pragma unroll
            for (int k = 0; k < 4; ++k) {
                acc0 += bf16raw2f((unsigned short)(v[k] & 0xFFFFu));
                acc1 += bf16raw2f((unsigned short)(v[k] >> 16));
            }
        }
        for (; i < npair; ++i) {
            int s = __shfl(idx, 2 * i + half, 64);
            unsigned v = *(const unsigned*)(hb + (size_t)s * DIM + fl * 2);
            acc0 += bf16raw2f((unsigned short)(v & 0xFFFFu));
            acc1 += bf16raw2f((unsigned short)(v >> 16));
        }
        if (m & 1) {
            int s = __shfl(idx, m - 1, 64);
            if (half == 0) {
                unsigned v = *(const unsigned*)(hb + (size_t)s * DIM + fl * 2);
                acc0 += bf16raw2f((unsigned short)(v & 0xFFFFu));
                acc1 += bf16raw2f((unsigned short)(v >> 16));
            }
        }
    }
    float t0 = acc0 + __shfl(acc0, fl + 32, 64);
    float t1 = acc1 + __shfl(acc1, fl + 32, 64);
    if (half == 0) {
        float inv = 1.0f / fmaxf((float)deg, 1.0f);
        float2 w;
        w.x = t0 * inv;
        w.y = t1 * inv;
        *(float2*)(mean + (size_t)n * DIM + fl * 2) = w;
    }
}

// ---------- aggregate (f32 fallback) ----------
__global__ __launch_bounds__(256) void aggregate_f32_kernel(
    const float* __restrict__ h,
    const int* __restrict__ ssrc,
    const int* __restrict__ noff,
    float* __restrict__ mean) {
    const int lane = threadIdx.x & 63;
    const int wave = (blockIdx.x * blockDim.x + threadIdx.x) >> 6;
    if (wave >= N_NODES) return;
    const int n = wave;
    const int start = noff[n];
    const int end = noff[n + 1];
    const int deg = end - start;

    float acc = 0.0f;
    for (int base = start; base < end; base += 64) {
        const int m = min(64, end - base);
        int idx = (lane < m) ? ssrc[base + lane] : 0;
        int i = 0;
        for (; i + 8 <= m; i += 8) {
            float v[8];
#pragma unroll
            for (int k = 0; k < 8; ++k) {
                int s = __shfl(idx, i + k, 64);
                v[k] = h[(size_t)s * DIM + lane];
            }
            acc += ((v[0] + v[1]) + (v[2] + v[3])) + ((v[4] + v[5]) + (v[6] + v[7]));
        }
        for (; i < m; ++i) {
            int s = __shfl(idx, i, 64);
            acc += h[(size_t)s * DIM + lane];
        }
    }
    mean[(size_t)n * DIM + lane] = acc / fmaxf((float)deg, 1.0f);
}

// ---------- combine: out = act(mean@Wl + h@Wr + b) ----------
// lane = node; wave = 16-wide output slice (j0 wave-uniform -> scalar W loads).
template <int LAYER, int SELFB>
__global__ __launch_bounds__(256) void combine_kernel(
    const float* __restrict__ mean,
    const float* __restrict__ hf,
    const unsigned short* __restrict__ hb,
    const float* __restrict__ Wl,
    const float* __restrict__ Wr,
    const float* __restrict__ bias,
    const float* __restrict__ u1,
    float* __restrict__ outf,
    unsigned short* __restrict__ outb) {
    const int lane = threadIdx.x & 63;
    const int wv = __builtin_amdgcn_readfirstlane((int)(threadIdx.x >> 6));
    const int j0 = wv * 16;
    const int n0 = blockIdx.x * 64 + lane;
    const int n = (n0 < N_NODES) ? n0 : (N_NODES - 1);
    const bool ok = (n0 < N_NODES);

    float acc[16];
#pragma unroll
    for (int j = 0; j < 16; ++j) acc[j] = bias[j0 + j];

    const float* mrow = mean + (size_t)n * DIM;
#pragma unroll
    for (int kc = 0; kc < DIM; kc += 4) {
        float4 am = *(const float4*)(mrow + kc);
        float a4[4] = {am.x, am.y, am.z, am.w};
#pragma unroll
        for (int kk = 0; kk < 4; ++kk) {
#pragma unroll
            for (int j = 0; j < 16; ++j)
                acc[j] += a4[kk] * Wl[(kc + kk) * DIM + j0 + j];
        }
    }

    if (SELFB == 0) {
        const float* hrow = hf + (size_t)n * DIM;
#pragma unroll
        for (int kc = 0; kc < DIM; kc += 4) {
            float4 ah = *(const float4*)(hrow + kc);
            float a4[4] = {ah.x, ah.y, ah.z, ah.w};
#pragma unroll
            for (int kk = 0; kk < 4; ++kk) {
#pragma unroll
                for (int j = 0; j < 16; ++j)
                    acc[j] += a4[kk] * Wr[(kc + kk) * DIM + j0 + j];
            }
        }
    } else {
        const unsigned short* hrow = hb + (size_t)n * DIM;
#pragma unroll
        for (int kc = 0; kc < DIM; kc += 8) {
            union { uint4 q; unsigned short s[8]; } u;
            u.q = *(const uint4*)(hrow + kc);
#pragma unroll
            for (int kk = 0; kk < 8; ++kk) {
                float a = bf16raw2f(u.s[kk]);
#pragma unroll
                for (int j = 0; j < 16; ++j)
                    acc[j] += a * Wr[(kc + kk) * DIM + j0 + j];
            }
        }
    }

#pragma unroll
    for (int j = 0; j < 16; ++j) acc[j] = fmaxf(acc[j], 0.0f);

    if (LAYER == 1) {
        const float* urow = u1 + (size_t)n * DIM + j0;
#pragma unroll
        for (int jc = 0; jc < 16; jc += 4) {
            float4 u4 = *(const float4*)(urow + jc);
            float uv[4] = {u4.x, u4.y, u4.z, u4.w};
#pragma unroll
            for (int t = 0; t < 4; ++t)
                acc[jc + t] = (uv[t] > 0.5f) ? acc[jc + t] * 2.0f : 0.0f;
        }
        if (ok) {
#pragma unroll
            for (int jc = 0; jc < 16; jc += 4) {
                ushort4 p;
                p.x = bf16bits(acc[jc]);
                p.y = bf16bits(acc[jc + 1]);
                p.z = bf16bits(acc[jc + 2]);
                p.w = bf16bits(acc[jc + 3]);
                *(ushort4*)(outb + (size_t)n * DIM + j0 + jc) = p;
            }
        }
    } else {
        if (ok) {
#pragma unroll
            for (int jc = 0; jc < 16; jc += 4) {
                float4 v;
                v.x = acc[jc]; v.y = acc[jc + 1]; v.z = acc[jc + 2]; v.w = acc[jc + 3];
                *(float4*)(outf + (size_t)n * DIM + j0 + jc) = v;
            }
        }
    }
}

extern "C" void kernel_launch(void* const* d_in, const int* in_sizes, int n_in,
                              void* d_out, int out_size, void* d_ws, size_t ws_size,
                              hipStream_t stream) {
    const float* x   = (const float*)d_in[0];
    const int*   ei  = (const int*)d_in[1];
    const float* u1  = (const float*)d_in[2];
    const float* W1l = (const float*)d_in[3];
    const float* W1r = (const float*)d_in[4];
    const float* b1  = (const float*)d_in[5];
    const float* W2l = (const float*)d_in[6];
    const float* W2r = (const float*)d_in[7];
    const float* b2  = (const float*)d_in[8];
    float* out = (float*)d_out;

    const int* src = ei;
    const int* dst = ei + N_EDGES;

    char* ws = (char*)d_ws;
    auto align256 = [](size_t v) { return (v + 255) & ~(size_t)255; };
    size_t o = 0;
    int* noff = (int*)(ws + o); o = align256(o + (size_t)(N_NODES + 1) * 4);
    int* bcnt = (int*)(ws + o); size_t zeroB = (size_t)NBUCK * 4; o = align256(o + zeroB);
    int* boff = (int*)(ws + o); o = align256(o + (size_t)NBUCK * 4);
    int* bcur = (int*)(ws + o); o = align256(o + (size_t)NBUCK * 4);
    int* ssrc = (int*)(ws + o); o = align256(o + (size_t)N_EDGES * 4);
    float* mean = (float*)(ws + o); o = align256(o + (size_t)N_NODES * DIM * 4);
    unsigned* tmp = (unsigned*)mean;   // aliased: tmp fully consumed before mean written
    unsigned short* h1b = (unsigned short*)(ws + o); o = align256(o + (size_t)N_NODES * DIM * 2);
    unsigned short* xb  = (unsigned short*)(ws + o);
    size_t need_xb = o + (size_t)N_NODES * DIM * 2;
    const bool useXb = (ws_size >= need_xb);   // ws_size constant across calls

    hipMemsetAsync(bcnt, 0, zeroB, stream);

    const int cbBlocks = (N_NODES + 63) / 64;            // 1563
    const int cvBlocks = (N_NODES * DIM / 4 + 255) / 256;
    const int aggBlocks = (N_NODES + 3) / 4;             // one wave per node

    hist_kernel<<<NBIN_H, 256, 0, stream>>>(dst, bcnt);
    bucket_scan_kernel<<<1, 1024, 0, stream>>>(bcnt, boff, bcur, noff);
    bin_kernel<<<NBIN_B, 256, 0, stream>>>(src, dst, bcur, tmp);
    bucket_sort_kernel<<<NBUCK, 256, 0, stream>>>(tmp, boff, bcnt, noff, ssrc);

    // ---- Layer 1 ----
    if (useXb) {
        cvt_bf16_kernel<<<cvBlocks, 256, 0, stream>>>(x, xb);
        aggregate_bf16_kernel<<<aggBlocks, 256, 0, stream>>>(xb, ssrc, noff, mean);
        combine_kernel<1, 1><<<cbBlocks, 256, 0, stream>>>(mean, nullptr, xb, W1l, W1r, b1,
                                                           u1, nullptr, h1b);
    } else {
        aggregate_f32_kernel<<<aggBlocks, 256, 0, stream>>>(x, ssrc, noff, mean);
        combine_kernel<1, 0><<<cbBlocks, 256, 0, stream>>>(mean, x, nullptr, W1l, W1r, b1,
                                                           u1, nullptr, h1b);
    }

    // ---- Layer 2 ----
    aggregate_bf16_kernel<<<aggBlocks, 256, 0, stream>>>(h1b, ssrc, noff, mean);
    combine_kernel<2, 1><<<cbBlocks, 256, 0, stream>>>(mean, nullptr, h1b, W2l, W2r, b2,
                                                       nullptr, out, nullptr);
}

// Round 10
// 294.048 us; speedup vs baseline: 4.4220x; 1.0997x over previous
//
#include <hip/hip_runtime.h>
#include <hip/hip_bf16.h>

#define N_NODES 100000
#define N_EDGES 1200000
#define DIM 64
#define NBUCK ((N_NODES + 127) / 128)            // 782 buckets of 128 nodes
#define HCHUNK 2048
#define NBIN_H ((N_EDGES + HCHUNK - 1) / HCHUNK) // 586
#define BCHUNK 2048
#define NBIN_B ((N_EDGES + BCHUNK - 1) / BCHUNK) // 586

typedef __attribute__((ext_vector_type(8))) short bf16x8;
typedef __attribute__((ext_vector_type(4))) float f32x4;

static __device__ __forceinline__ unsigned short bf16bits(float f) {
    __hip_bfloat16 h = __float2bfloat16(f);
    return *reinterpret_cast<unsigned short*>(&h);
}
static __device__ __forceinline__ float bf16raw2f(unsigned short s) {
    return __uint_as_float(((unsigned)s) << 16);
}

// ---------- hist: per-bucket edge counts (LDS-preaggregated) ----------
__global__ __launch_bounds__(256) void hist_kernel(const int* __restrict__ dst,
                                                   int* __restrict__ bcnt) {
    __shared__ int lb[NBUCK];
    for (int i = threadIdx.x; i < NBUCK; i += 256) lb[i] = 0;
    __syncthreads();
    const int e0 = blockIdx.x * HCHUNK;
    const int e1 = min(e0 + HCHUNK, N_EDGES);
    for (int e = e0 + threadIdx.x; e < e1; e += 256)
        atomicAdd(&lb[dst[e] >> 7], 1);
    __syncthreads();
    for (int i = threadIdx.x; i < NBUCK; i += 256) {
        int c = lb[i];
        if (c) atomicAdd(&bcnt[i], c);
    }
}

// ---------- exclusive scan of bucket counts (one block) ----------
__global__ __launch_bounds__(1024) void bucket_scan_kernel(const int* __restrict__ bcnt,
                                                           int* __restrict__ boff,
                                                           int* __restrict__ bcur,
                                                           int* __restrict__ noff) {
    __shared__ int tmp[1024];
    const int t = threadIdx.x;
    int v = (t < NBUCK) ? bcnt[t] : 0;
    tmp[t] = v;
    __syncthreads();
    for (int ofs = 1; ofs < 1024; ofs <<= 1) {
        int x = (t >= ofs) ? tmp[t - ofs] : 0;
        __syncthreads();
        tmp[t] += x;
        __syncthreads();
    }
    if (t < NBUCK) {
        int ex = tmp[t] - v;
        boff[t] = ex;
        bcur[t] = ex;
    }
    if (t == 0) noff[N_NODES] = N_EDGES;   // sentinel: deg = noff[n+1]-noff[n]
}

// ---------- bin: scatter edges to bucket granularity, packed ----------
// pack = (dstLocal << 17) | src   (src < 2^17, dstLocal < 128)
__global__ __launch_bounds__(256) void bin_kernel(const int* __restrict__ src,
                                                  const int* __restrict__ dst,
                                                  int* __restrict__ bcur,
                                                  unsigned* __restrict__ tmp) {
    __shared__ int lcnt[NBUCK];
    __shared__ int lbase[NBUCK];
    const int tid = threadIdx.x;
    for (int i = tid; i < NBUCK; i += 256) lcnt[i] = 0;
    __syncthreads();
    const int e0 = blockIdx.x * BCHUNK;
    const int e1 = min(e0 + BCHUNK, N_EDGES);
    for (int e = e0 + tid; e < e1; e += 256)
        atomicAdd(&lcnt[dst[e] >> 7], 1);
    __syncthreads();
    for (int i = tid; i < NBUCK; i += 256) {
        int c = lcnt[i];
        lbase[i] = c ? atomicAdd(&bcur[i], c) : 0;
    }
    __syncthreads();
    for (int i = tid; i < NBUCK; i += 256) lcnt[i] = 0;
    __syncthreads();
    for (int e = e0 + tid; e < e1; e += 256) {
        int d = dst[e];
        int b = d >> 7;
        int r = atomicAdd(&lcnt[b], 1);
        tmp[lbase[b] + r] = ((unsigned)(d & 127) << 17) | (unsigned)src[e];
    }
}

// ---------- bucket_sort: per-node sort within each bucket ----------
__global__ __launch_bounds__(256) void bucket_sort_kernel(
    const unsigned* __restrict__ tmp,
    const int* __restrict__ boff,
    const int* __restrict__ bcnt,
    int* __restrict__ noff,
    int* __restrict__ ssrc) {
    __shared__ int lcnt[128];
    __shared__ int lofs[128];
    const int tid = threadIdx.x;
    const int b = blockIdx.x;
    const int start = boff[b];
    const int len = bcnt[b];

    if (tid < 128) lcnt[tid] = 0;
    __syncthreads();
    for (int i = tid; i < len; i += 256)
        atomicAdd(&lcnt[tmp[start + i] >> 17], 1);
    __syncthreads();
    if (tid < 128) lofs[tid] = lcnt[tid];
    __syncthreads();
    for (int ofs = 1; ofs < 128; ofs <<= 1) {
        int v = (tid < 128 && tid >= ofs) ? lofs[tid - ofs] : 0;
        __syncthreads();
        if (tid < 128) lofs[tid] += v;
        __syncthreads();
    }
    if (tid < 128) {
        int ex = lofs[tid] - lcnt[tid];
        int n = b * 128 + tid;
        if (n < N_NODES) noff[n] = start + ex;
        lcnt[tid] = ex;
    }
    __syncthreads();
    for (int i = tid; i < len; i += 256) {
        unsigned v = tmp[start + i];
        int d = v >> 17;
        int r = atomicAdd(&lcnt[d], 1);
        ssrc[start + r] = (int)(v & 0x1FFFFu);
    }
}

// ---------- f32 -> bf16 feature-table conversion ----------
__global__ __launch_bounds__(256) void cvt_bf16_kernel(const float* __restrict__ in,
                                                       unsigned short* __restrict__ out) {
    int i = blockIdx.x * blockDim.x + threadIdx.x;
    const int total = N_NODES * DIM / 4;
    if (i >= total) return;
    float4 v = ((const float4*)in)[i];
    ushort4 p;
    p.x = bf16bits(v.x); p.y = bf16bits(v.y); p.z = bf16bits(v.z); p.w = bf16bits(v.w);
    ((ushort4*)out)[i] = p;
}

// ---------- weight transpose+cvt: WT[c][k] = bf16(Wcat[k][c]), [64][128] ----------
// block 0: W1 (Wl=W1_l, Wr=W1_r) -> w1t; block 1: W2 -> w2t
__global__ __launch_bounds__(256) void cvt_wt_kernel(const float* __restrict__ W1l,
                                                     const float* __restrict__ W1r,
                                                     const float* __restrict__ W2l,
                                                     const float* __restrict__ W2r,
                                                     unsigned short* __restrict__ w1t,
                                                     unsigned short* __restrict__ w2t) {
    const float* Wl = blockIdx.x ? W2l : W1l;
    const float* Wr = blockIdx.x ? W2r : W1r;
    unsigned short* wt = blockIdx.x ? w2t : w1t;
    for (int i = threadIdx.x; i < 64 * 128; i += 256) {
        int c = i >> 7;
        int k = i & 127;
        float v = (k < 64) ? Wl[k * 64 + c] : Wr[(k - 64) * 64 + c];
        wt[c * 128 + k] = bf16bits(v);
    }
}

// ---------- aggregate (bf16): 2 edges per wave, 32 lanes each; bf16 mean out ----------
__global__ __launch_bounds__(256) void aggregate_bf16_kernel(
    const unsigned short* __restrict__ hb,
    const int* __restrict__ ssrc,
    const int* __restrict__ noff,
    unsigned short* __restrict__ meanb) {
    const int lane = threadIdx.x & 63;
    const int wave = (blockIdx.x * blockDim.x + threadIdx.x) >> 6;
    if (wave >= N_NODES) return;
    const int n = wave;
    const int start = noff[n];
    const int end = noff[n + 1];
    const int deg = end - start;
    const int half = lane >> 5;
    const int fl = lane & 31;

    float acc0 = 0.0f, acc1 = 0.0f;
    for (int base = start; base < end; base += 64) {
        const int m = min(64, end - base);
        int idx = (lane < m) ? ssrc[base + lane] : 0;
        const int npair = m >> 1;
        int i = 0;
        for (; i + 4 <= npair; i += 4) {
            unsigned v[4];
#pragma unroll
            for (int k = 0; k < 4; ++k) {
                int s = __shfl(idx, 2 * (i + k) + half, 64);
                v[k] = *(const unsigned*)(hb + (size_t)s * DIM + fl * 2);
            }
#pragma unroll
            for (int k = 0; k < 4; ++k) {
                acc0 += bf16raw2f((unsigned short)(v[k] & 0xFFFFu));
                acc1 += bf16raw2f((unsigned short)(v[k] >> 16));
            }
        }
        for (; i < npair; ++i) {
            int s = __shfl(idx, 2 * i + half, 64);
            unsigned v = *(const unsigned*)(hb + (size_t)s * DIM + fl * 2);
            acc0 += bf16raw2f((unsigned short)(v & 0xFFFFu));
            acc1 += bf16raw2f((unsigned short)(v >> 16));
        }
        if (m & 1) {
            int s = __shfl(idx, m - 1, 64);
            if (half == 0) {
                unsigned v = *(const unsigned*)(hb + (size_t)s * DIM + fl * 2);
                acc0 += bf16raw2f((unsigned short)(v & 0xFFFFu));
                acc1 += bf16raw2f((unsigned short)(v >> 16));
            }
        }
    }
    float t0 = acc0 + __shfl(acc0, fl + 32, 64);
    float t1 = acc1 + __shfl(acc1, fl + 32, 64);
    if (half == 0) {
        float inv = 1.0f / fmaxf((float)deg, 1.0f);
        unsigned pk = ((unsigned)bf16bits(t1 * inv) << 16) | (unsigned)bf16bits(t0 * inv);
        *(unsigned*)(meanb + (size_t)n * DIM + fl * 2) = pk;
    }
}

// ---------- combine via MFMA: out = act([mean|h] @ [Wl;Wr] + b) ----------
// One wave per 16 nodes. A-frag: row = lane&15, k = kblk*32 + (lane>>4)*8 + j.
// B-frag (WT[c][k]): col = lane&15 (within tile), same k mapping.
// C/D: col = lane&15, row = (lane>>4)*4 + reg   [m89-verified].
template <int LAYER>
__global__ __launch_bounds__(256) void combine_mfma_kernel(
    const unsigned short* __restrict__ meanb,
    const unsigned short* __restrict__ selfb,   // xb (L1) or h1b (L2)
    const unsigned short* __restrict__ WT,      // [64][128] bf16
    const float* __restrict__ bias,
    const float* __restrict__ u1,
    float* __restrict__ outf,                   // L2: final out
    unsigned short* __restrict__ outb) {        // L1: h1b
    const int lane = threadIdx.x & 63;
    const int wid = (blockIdx.x * blockDim.x + threadIdx.x) >> 6;
    const int n0 = wid * 16;
    if (n0 >= N_NODES) return;
    const int rl = lane & 15;
    const int kg = lane >> 4;

    const size_t arow = (size_t)(n0 + rl) * DIM;
    bf16x8 a0 = *(const bf16x8*)(meanb + arow + 0 + kg * 8);
    bf16x8 a1 = *(const bf16x8*)(meanb + arow + 32 + kg * 8);
    bf16x8 a2 = *(const bf16x8*)(selfb + arow + 0 + kg * 8);
    bf16x8 a3 = *(const bf16x8*)(selfb + arow + 32 + kg * 8);

#pragma unroll
    for (int ct = 0; ct < 4; ++ct) {
        const int col = ct * 16 + rl;
        const unsigned short* wcol = WT + (size_t)col * 128 + kg * 8;
        bf16x8 b0 = *(const bf16x8*)(wcol + 0);
        bf16x8 b1 = *(const bf16x8*)(wcol + 32);
        bf16x8 b2 = *(const bf16x8*)(wcol + 64);
        bf16x8 b3 = *(const bf16x8*)(wcol + 96);
        float bv = bias[col];
        f32x4 acc = {bv, bv, bv, bv};
        acc = __builtin_amdgcn_mfma_f32_16x16x32_bf16(a0, b0, acc, 0, 0, 0);
        acc = __builtin_amdgcn_mfma_f32_16x16x32_bf16(a1, b1, acc, 0, 0, 0);
        acc = __builtin_amdgcn_mfma_f32_16x16x32_bf16(a2, b2, acc, 0, 0, 0);
        acc = __builtin_amdgcn_mfma_f32_16x16x32_bf16(a3, b3, acc, 0, 0, 0);

        const int rowb = n0 + kg * 4;
#pragma unroll
        for (int r = 0; r < 4; ++r) {
            float v = fmaxf(acc[r], 0.0f);
            const size_t oidx = (size_t)(rowb + r) * DIM + col;
            if (LAYER == 1) {
                float u = u1[oidx];
                v = (u > 0.5f) ? v * 2.0f : 0.0f;
                outb[oidx] = bf16bits(v);
            } else {
                outf[oidx] = v;
            }
        }
    }
}

extern "C" void kernel_launch(void* const* d_in, const int* in_sizes, int n_in,
                              void* d_out, int out_size, void* d_ws, size_t ws_size,
                              hipStream_t stream) {
    const float* x   = (const float*)d_in[0];
    const int*   ei  = (const int*)d_in[1];
    const float* u1  = (const float*)d_in[2];
    const float* W1l = (const float*)d_in[3];
    const float* W1r = (const float*)d_in[4];
    const float* b1  = (const float*)d_in[5];
    const float* W2l = (const float*)d_in[6];
    const float* W2r = (const float*)d_in[7];
    const float* b2  = (const float*)d_in[8];
    float* out = (float*)d_out;

    const int* src = ei;
    const int* dst = ei + N_EDGES;

    char* ws = (char*)d_ws;
    auto align256 = [](size_t v) { return (v + 255) & ~(size_t)255; };
    size_t o = 0;
    int* noff = (int*)(ws + o); o = align256(o + (size_t)(N_NODES + 1) * 4);
    int* bcnt = (int*)(ws + o); size_t zeroB = (size_t)NBUCK * 4; o = align256(o + zeroB);
    int* boff = (int*)(ws + o); o = align256(o + (size_t)NBUCK * 4);
    int* bcur = (int*)(ws + o); o = align256(o + (size_t)NBUCK * 4);
    unsigned short* w1t = (unsigned short*)(ws + o); o = align256(o + (size_t)64 * 128 * 2);
    unsigned short* w2t = (unsigned short*)(ws + o); o = align256(o + (size_t)64 * 128 * 2);
    int* ssrc = (int*)(ws + o); o = align256(o + (size_t)N_EDGES * 4);
    unsigned short* meanb = (unsigned short*)(ws + o); o = align256(o + (size_t)N_NODES * DIM * 2);
    unsigned* tmp = (unsigned*)meanb;   // aliased: tmp consumed (bucket_sort) before meanb written
    unsigned short* h1b = (unsigned short*)(ws + o); o = align256(o + (size_t)N_NODES * DIM * 2);
    unsigned short* xb  = (unsigned short*)(ws + o); o += (size_t)N_NODES * DIM * 2;
    // total ~44 MB

    hipMemsetAsync(bcnt, 0, zeroB, stream);

    const int cbBlocks = (N_NODES / 16 + 3) / 4;         // 1563 (6250 waves)
    const int cvBlocks = (N_NODES * DIM / 4 + 255) / 256;
    const int aggBlocks = (N_NODES + 3) / 4;             // one wave per node

    hist_kernel<<<NBIN_H, 256, 0, stream>>>(dst, bcnt);
    bucket_scan_kernel<<<1, 1024, 0, stream>>>(bcnt, boff, bcur, noff);
    bin_kernel<<<NBIN_B, 256, 0, stream>>>(src, dst, bcur, tmp);
    bucket_sort_kernel<<<NBUCK, 256, 0, stream>>>(tmp, boff, bcnt, noff, ssrc);

    cvt_bf16_kernel<<<cvBlocks, 256, 0, stream>>>(x, xb);
    cvt_wt_kernel<<<2, 256, 0, stream>>>(W1l, W1r, W2l, W2r, w1t, w2t);

    // ---- Layer 1 ----
    aggregate_bf16_kernel<<<aggBlocks, 256, 0, stream>>>(xb, ssrc, noff, meanb);
    combine_mfma_kernel<1><<<cbBlocks, 256, 0, stream>>>(meanb, xb, w1t, b1, u1,
                                                         nullptr, h1b);

    // ---- Layer 2 ----
    aggregate_bf16_kernel<<<aggBlocks, 256, 0, stream>>>(h1b, ssrc, noff, meanb);
    combine_mfma_kernel<2><<<cbBlocks, 256, 0, stream>>>(meanb, h1b, w2t, b2, nullptr,
                                                         out, nullptr);
}

// Round 11
// 293.933 us; speedup vs baseline: 4.4238x; 1.0004x over previous
//
#include <hip/hip_runtime.h>
#include <hip/hip_bf16.h>

#define N_NODES 100000
#define N_EDGES 1200000
#define DIM 64
#define NBUCK ((N_NODES + 127) / 128)            // 782 buckets of 128 nodes
#define HCHUNK 2048
#define NBIN_H ((N_EDGES + HCHUNK - 1) / HCHUNK) // 586
#define BCHUNK 2048
#define NBIN_B ((N_EDGES + BCHUNK - 1) / BCHUNK) // 586

typedef __attribute__((ext_vector_type(8))) short bf16x8;
typedef __attribute__((ext_vector_type(4))) float f32x4;

static __device__ __forceinline__ unsigned short bf16bits(float f) {
    __hip_bfloat16 h = __float2bfloat16(f);
    return *reinterpret_cast<unsigned short*>(&h);
}
static __device__ __forceinline__ float bf16raw2f(unsigned short s) {
    return __uint_as_float(((unsigned)s) << 16);
}

// ---------- hist: per-bucket edge counts (LDS-preaggregated) ----------
__global__ __launch_bounds__(256) void hist_kernel(const int* __restrict__ dst,
                                                   int* __restrict__ bcnt) {
    __shared__ int lb[NBUCK];
    for (int i = threadIdx.x; i < NBUCK; i += 256) lb[i] = 0;
    __syncthreads();
    const int e0 = blockIdx.x * HCHUNK;
    const int e1 = min(e0 + HCHUNK, N_EDGES);
    for (int e = e0 + threadIdx.x; e < e1; e += 256)
        atomicAdd(&lb[dst[e] >> 7], 1);
    __syncthreads();
    for (int i = threadIdx.x; i < NBUCK; i += 256) {
        int c = lb[i];
        if (c) atomicAdd(&bcnt[i], c);
    }
}

// ---------- exclusive scan of bucket counts (one block) ----------
__global__ __launch_bounds__(1024) void bucket_scan_kernel(const int* __restrict__ bcnt,
                                                           int* __restrict__ boff,
                                                           int* __restrict__ bcur,
                                                           int* __restrict__ noff) {
    __shared__ int tmp[1024];
    const int t = threadIdx.x;
    int v = (t < NBUCK) ? bcnt[t] : 0;
    tmp[t] = v;
    __syncthreads();
    for (int ofs = 1; ofs < 1024; ofs <<= 1) {
        int x = (t >= ofs) ? tmp[t - ofs] : 0;
        __syncthreads();
        tmp[t] += x;
        __syncthreads();
    }
    if (t < NBUCK) {
        int ex = tmp[t] - v;
        boff[t] = ex;
        bcur[t] = ex;
    }
    if (t == 0) noff[N_NODES] = N_EDGES;   // sentinel: deg = noff[n+1]-noff[n]
}

// ---------- bin: scatter edges to bucket granularity, packed ----------
// pack = (dstLocal << 17) | src   (src < 2^17, dstLocal < 128)
__global__ __launch_bounds__(256) void bin_kernel(const int* __restrict__ src,
                                                  const int* __restrict__ dst,
                                                  int* __restrict__ bcur,
                                                  unsigned* __restrict__ tmp) {
    __shared__ int lcnt[NBUCK];
    __shared__ int lbase[NBUCK];
    const int tid = threadIdx.x;
    for (int i = tid; i < NBUCK; i += 256) lcnt[i] = 0;
    __syncthreads();
    const int e0 = blockIdx.x * BCHUNK;
    const int e1 = min(e0 + BCHUNK, N_EDGES);
    for (int e = e0 + tid; e < e1; e += 256)
        atomicAdd(&lcnt[dst[e] >> 7], 1);
    __syncthreads();
    for (int i = tid; i < NBUCK; i += 256) {
        int c = lcnt[i];
        lbase[i] = c ? atomicAdd(&bcur[i], c) : 0;
    }
    __syncthreads();
    for (int i = tid; i < NBUCK; i += 256) lcnt[i] = 0;
    __syncthreads();
    for (int e = e0 + tid; e < e1; e += 256) {
        int d = dst[e];
        int b = d >> 7;
        int r = atomicAdd(&lcnt[b], 1);
        tmp[lbase[b] + r] = ((unsigned)(d & 127) << 17) | (unsigned)src[e];
    }
}

// ---------- bucket_sort: per-node sort within each bucket ----------
__global__ __launch_bounds__(256) void bucket_sort_kernel(
    const unsigned* __restrict__ tmp,
    const int* __restrict__ boff,
    const int* __restrict__ bcnt,
    int* __restrict__ noff,
    int* __restrict__ ssrc) {
    __shared__ int lcnt[128];
    __shared__ int lofs[128];
    const int tid = threadIdx.x;
    const int b = blockIdx.x;
    const int start = boff[b];
    const int len = bcnt[b];

    if (tid < 128) lcnt[tid] = 0;
    __syncthreads();
    for (int i = tid; i < len; i += 256)
        atomicAdd(&lcnt[tmp[start + i] >> 17], 1);
    __syncthreads();
    if (tid < 128) lofs[tid] = lcnt[tid];
    __syncthreads();
    for (int ofs = 1; ofs < 128; ofs <<= 1) {
        int v = (tid < 128 && tid >= ofs) ? lofs[tid - ofs] : 0;
        __syncthreads();
        if (tid < 128) lofs[tid] += v;
        __syncthreads();
    }
    if (tid < 128) {
        int ex = lofs[tid] - lcnt[tid];
        int n = b * 128 + tid;
        if (n < N_NODES) noff[n] = start + ex;
        lcnt[tid] = ex;
    }
    __syncthreads();
    for (int i = tid; i < len; i += 256) {
        unsigned v = tmp[start + i];
        int d = v >> 17;
        int r = atomicAdd(&lcnt[d], 1);
        ssrc[start + r] = (int)(v & 0x1FFFFu);
    }
}

// ---------- prep: blocks 0,1 -> weight transpose+cvt; blocks 2.. -> x->bf16 ----------
__global__ __launch_bounds__(256) void prep_kernel(const float* __restrict__ x,
                                                   const float* __restrict__ W1l,
                                                   const float* __restrict__ W1r,
                                                   const float* __restrict__ W2l,
                                                   const float* __restrict__ W2r,
                                                   unsigned short* __restrict__ xb,
                                                   unsigned short* __restrict__ w1t,
                                                   unsigned short* __restrict__ w2t) {
    if (blockIdx.x < 2) {
        const float* Wl = blockIdx.x ? W2l : W1l;
        const float* Wr = blockIdx.x ? W2r : W1r;
        unsigned short* wt = blockIdx.x ? w2t : w1t;
        for (int i = threadIdx.x; i < 64 * 128; i += 256) {
            int c = i >> 7;
            int k = i & 127;
            float v = (k < 64) ? Wl[k * 64 + c] : Wr[(k - 64) * 64 + c];
            wt[c * 128 + k] = bf16bits(v);
        }
        return;
    }
    int i = (blockIdx.x - 2) * 256 + threadIdx.x;
    const int total = N_NODES * DIM / 4;
    if (i >= total) return;
    float4 v = ((const float4*)x)[i];
    ushort4 p;
    p.x = bf16bits(v.x); p.y = bf16bits(v.y); p.z = bf16bits(v.z); p.w = bf16bits(v.w);
    ((ushort4*)xb)[i] = p;
}

// ---------- aggregate (bf16): 4 edges per wave, 16 lanes x uint2 each ----------
// lane = g*16 + r: group g handles edge 4i+g, lane reads features r*4..r*4+3.
__global__ __launch_bounds__(256) void aggregate_bf16_kernel(
    const unsigned short* __restrict__ hb,
    const int* __restrict__ ssrc,
    const int* __restrict__ noff,
    unsigned short* __restrict__ meanb) {
    const int lane = threadIdx.x & 63;
    const int wave = (blockIdx.x * blockDim.x + threadIdx.x) >> 6;
    if (wave >= N_NODES) return;
    const int n = wave;
    const int start = noff[n];
    const int end = noff[n + 1];
    const int deg = end - start;
    const int g = lane >> 4;
    const int r = lane & 15;

    float a0 = 0.0f, a1 = 0.0f, a2 = 0.0f, a3 = 0.0f;
    for (int base = start; base < end; base += 64) {
        const int m = min(64, end - base);
        int idx = (lane < m) ? ssrc[base + lane] : 0;
        const int nq = m >> 2;
        int i = 0;
        for (; i + 4 <= nq; i += 4) {
            uint2 v[4];
#pragma unroll
            for (int k = 0; k < 4; ++k) {
                int s = __shfl(idx, 4 * (i + k) + g, 64);
                v[k] = *(const uint2*)(hb + (size_t)s * DIM + r * 4);
            }
#pragma unroll
            for (int k = 0; k < 4; ++k) {
                a0 += bf16raw2f((unsigned short)(v[k].x & 0xFFFFu));
                a1 += bf16raw2f((unsigned short)(v[k].x >> 16));
                a2 += bf16raw2f((unsigned short)(v[k].y & 0xFFFFu));
                a3 += bf16raw2f((unsigned short)(v[k].y >> 16));
            }
        }
        for (; i < nq; ++i) {
            int s = __shfl(idx, 4 * i + g, 64);
            uint2 v = *(const uint2*)(hb + (size_t)s * DIM + r * 4);
            a0 += bf16raw2f((unsigned short)(v.x & 0xFFFFu));
            a1 += bf16raw2f((unsigned short)(v.x >> 16));
            a2 += bf16raw2f((unsigned short)(v.y & 0xFFFFu));
            a3 += bf16raw2f((unsigned short)(v.y >> 16));
        }
        const int tail = m & 3;
        if (tail) {
            const int e0 = nq * 4;
            int s = __shfl(idx, min(e0 + g, m - 1), 64);
            if (g < tail) {
                uint2 v = *(const uint2*)(hb + (size_t)s * DIM + r * 4);
                a0 += bf16raw2f((unsigned short)(v.x & 0xFFFFu));
                a1 += bf16raw2f((unsigned short)(v.x >> 16));
                a2 += bf16raw2f((unsigned short)(v.y & 0xFFFFu));
                a3 += bf16raw2f((unsigned short)(v.y >> 16));
            }
        }
    }
    // reduce across the 4 groups (xor 16, then 32)
    a0 += __shfl_xor(a0, 16, 64); a0 += __shfl_xor(a0, 32, 64);
    a1 += __shfl_xor(a1, 16, 64); a1 += __shfl_xor(a1, 32, 64);
    a2 += __shfl_xor(a2, 16, 64); a2 += __shfl_xor(a2, 32, 64);
    a3 += __shfl_xor(a3, 16, 64); a3 += __shfl_xor(a3, 32, 64);

    if (g == 0) {
        float inv = 1.0f / fmaxf((float)deg, 1.0f);
        uint2 w;
        w.x = ((unsigned)bf16bits(a1 * inv) << 16) | (unsigned)bf16bits(a0 * inv);
        w.y = ((unsigned)bf16bits(a3 * inv) << 16) | (unsigned)bf16bits(a2 * inv);
        *(uint2*)(meanb + (size_t)n * DIM + r * 4) = w;
    }
}

// ---------- combine via MFMA: out = act([mean|h] @ [Wl;Wr] + b) ----------
// One wave per 16 nodes. A-frag: row = lane&15, k = kblk*32 + (lane>>4)*8 + j.
// B-frag (WT[c][k]): col = lane&15, same k mapping.
// C/D: col = lane&15, row = (lane>>4)*4 + reg   [m89-verified].
template <int LAYER>
__global__ __launch_bounds__(256) void combine_mfma_kernel(
    const unsigned short* __restrict__ meanb,
    const unsigned short* __restrict__ selfb,   // xb (L1) or h1b (L2)
    const unsigned short* __restrict__ WT,      // [64][128] bf16
    const float* __restrict__ bias,
    const float* __restrict__ u1,
    float* __restrict__ outf,                   // L2: final out
    unsigned short* __restrict__ outb) {        // L1: h1b
    const int lane = threadIdx.x & 63;
    const int wid = (blockIdx.x * blockDim.x + threadIdx.x) >> 6;
    const int n0 = wid * 16;
    if (n0 >= N_NODES) return;
    const int rl = lane & 15;
    const int kg = lane >> 4;

    const size_t arow = (size_t)(n0 + rl) * DIM;
    bf16x8 a0 = *(const bf16x8*)(meanb + arow + 0 + kg * 8);
    bf16x8 a1 = *(const bf16x8*)(meanb + arow + 32 + kg * 8);
    bf16x8 a2 = *(const bf16x8*)(selfb + arow + 0 + kg * 8);
    bf16x8 a3 = *(const bf16x8*)(selfb + arow + 32 + kg * 8);

#pragma unroll
    for (int ct = 0; ct < 4; ++ct) {
        const int col = ct * 16 + rl;
        const unsigned short* wcol = WT + (size_t)col * 128 + kg * 8;
        bf16x8 b0 = *(const bf16x8*)(wcol + 0);
        bf16x8 b1 = *(const bf16x8*)(wcol + 32);
        bf16x8 b2 = *(const bf16x8*)(wcol + 64);
        bf16x8 b3 = *(const bf16x8*)(wcol + 96);
        float bv = bias[col];
        f32x4 acc = {bv, bv, bv, bv};
        acc = __builtin_amdgcn_mfma_f32_16x16x32_bf16(a0, b0, acc, 0, 0, 0);
        acc = __builtin_amdgcn_mfma_f32_16x16x32_bf16(a1, b1, acc, 0, 0, 0);
        acc = __builtin_amdgcn_mfma_f32_16x16x32_bf16(a2, b2, acc, 0, 0, 0);
        acc = __builtin_amdgcn_mfma_f32_16x16x32_bf16(a3, b3, acc, 0, 0, 0);

        const int rowb = n0 + kg * 4;
#pragma unroll
        for (int r = 0; r < 4; ++r) {
            float v = fmaxf(acc[r], 0.0f);
            const size_t oidx = (size_t)(rowb + r) * DIM + col;
            if (LAYER == 1) {
                float u = u1[oidx];
                v = (u > 0.5f) ? v * 2.0f : 0.0f;
                outb[oidx] = bf16bits(v);
            } else {
                outf[oidx] = v;
            }
        }
    }
}

extern "C" void kernel_launch(void* const* d_in, const int* in_sizes, int n_in,
                              void* d_out, int out_size, void* d_ws, size_t ws_size,
                              hipStream_t stream) {
    const float* x   = (const float*)d_in[0];
    const int*   ei  = (const int*)d_in[1];
    const float* u1  = (const float*)d_in[2];
    const float* W1l = (const float*)d_in[3];
    const float* W1r = (const float*)d_in[4];
    const float* b1  = (const float*)d_in[5];
    const float* W2l = (const float*)d_in[6];
    const float* W2r = (const float*)d_in[7];
    const float* b2  = (const float*)d_in[8];
    float* out = (float*)d_out;

    const int* src = ei;
    const int* dst = ei + N_EDGES;

    char* ws = (char*)d_ws;
    auto align256 = [](size_t v) { return (v + 255) & ~(size_t)255; };
    size_t o = 0;
    int* noff = (int*)(ws + o); o = align256(o + (size_t)(N_NODES + 1) * 4);
    int* bcnt = (int*)(ws + o); size_t zeroB = (size_t)NBUCK * 4; o = align256(o + zeroB);
    int* boff = (int*)(ws + o); o = align256(o + (size_t)NBUCK * 4);
    int* bcur = (int*)(ws + o); o = align256(o + (size_t)NBUCK * 4);
    unsigned short* w1t = (unsigned short*)(ws + o); o = align256(o + (size_t)64 * 128 * 2);
    unsigned short* w2t = (unsigned short*)(ws + o); o = align256(o + (size_t)64 * 128 * 2);
    int* ssrc = (int*)(ws + o); o = align256(o + (size_t)N_EDGES * 4);
    unsigned short* meanb = (unsigned short*)(ws + o); o = align256(o + (size_t)N_NODES * DIM * 2);
    unsigned* tmp = (unsigned*)meanb;   // aliased: tmp consumed (bucket_sort) before meanb written
    unsigned short* h1b = (unsigned short*)(ws + o); o = align256(o + (size_t)N_NODES * DIM * 2);
    unsigned short* xb  = (unsigned short*)(ws + o); o += (size_t)N_NODES * DIM * 2;
    // total ~44 MB

    hipMemsetAsync(bcnt, 0, zeroB, stream);

    const int cbBlocks = (N_NODES / 16 + 3) / 4;         // 1563 (6250 waves)
    const int cvBlocks = (N_NODES * DIM / 4 + 255) / 256;
    const int aggBlocks = (N_NODES + 3) / 4;             // one wave per node

    hist_kernel<<<NBIN_H, 256, 0, stream>>>(dst, bcnt);
    bucket_scan_kernel<<<1, 1024, 0, stream>>>(bcnt, boff, bcur, noff);
    bin_kernel<<<NBIN_B, 256, 0, stream>>>(src, dst, bcur, tmp);
    bucket_sort_kernel<<<NBUCK, 256, 0, stream>>>(tmp, boff, bcnt, noff, ssrc);

    prep_kernel<<<cvBlocks + 2, 256, 0, stream>>>(x, W1l, W1r, W2l, W2r, xb, w1t, w2t);

    // ---- Layer 1 ----
    aggregate_bf16_kernel<<<aggBlocks, 256, 0, stream>>>(xb, ssrc, noff, meanb);
    combine_mfma_kernel<1><<<cbBlocks, 256, 0, stream>>>(meanb, xb, w1t, b1, u1,
                                                         nullptr, h1b);

    // ---- Layer 2 ----
    aggregate_bf16_kernel<<<aggBlocks, 256, 0, stream>>>(h1b, ssrc, noff, meanb);
    combine_mfma_kernel<2><<<cbBlocks, 256, 0, stream>>>(meanb, h1b, w2t, b2, nullptr,
                                                         out, nullptr);
}

// Round 12
// 268.611 us; speedup vs baseline: 4.8408x; 1.0943x over previous
//
#include <hip/hip_runtime.h>
#include <hip/hip_bf16.h>

#define N_NODES 100000
#define N_EDGES 1200000
#define DIM 64
#define NBUCK ((N_NODES + 127) / 128)            // 782 buckets of 128 nodes
#define CAP 2048                                 // fixed bucket capacity (13 sigma)
#define BCHUNK 2048
#define NBIN_B ((N_EDGES + BCHUNK - 1) / BCHUNK) // 586
#define CVBLKS ((N_NODES * DIM / 4 + 255) / 256) // 6250

typedef __attribute__((ext_vector_type(8))) short bf16x8;
typedef __attribute__((ext_vector_type(4))) float f32x4;

static __device__ __forceinline__ unsigned short bf16bits(float f) {
    __hip_bfloat16 h = __float2bfloat16(f);
    return *reinterpret_cast<unsigned short*>(&h);
}
static __device__ __forceinline__ float bf16raw2f(unsigned short s) {
    return __uint_as_float(((unsigned)s) << 16);
}

// ---------- bin + prep fused ----------
// blocks [0, NBIN_B): scatter edges to fixed-stride buckets (pack = dstLocal<<17 | src)
// blocks [NBIN_B, NBIN_B+2): weight transpose+cvt -> w1t/w2t
// blocks [NBIN_B+2, ...): x -> bf16
__global__ __launch_bounds__(256) void bin_prep_kernel(
    const int* __restrict__ src,
    const int* __restrict__ dst,
    const float* __restrict__ x,
    const float* __restrict__ W1l,
    const float* __restrict__ W1r,
    const float* __restrict__ W2l,
    const float* __restrict__ W2r,
    int* __restrict__ bcnt,          // zeroed; becomes per-bucket count
    unsigned* __restrict__ tmp,      // [NBUCK * CAP]
    unsigned short* __restrict__ xb,
    unsigned short* __restrict__ w1t,
    unsigned short* __restrict__ w2t) {
    __shared__ int lcnt[NBUCK];
    __shared__ int lbase[NBUCK];
    const int bid = blockIdx.x;
    const int tid = threadIdx.x;

    if (bid < NBIN_B) {
        for (int i = tid; i < NBUCK; i += 256) lcnt[i] = 0;
        __syncthreads();
        const int e0 = bid * BCHUNK;
        const int e1 = min(e0 + BCHUNK, N_EDGES);
        for (int e = e0 + tid; e < e1; e += 256)
            atomicAdd(&lcnt[dst[e] >> 7], 1);
        __syncthreads();
        for (int i = tid; i < NBUCK; i += 256) {
            int c = lcnt[i];
            lbase[i] = c ? (i * CAP + atomicAdd(&bcnt[i], c)) : 0;
        }
        __syncthreads();
        for (int i = tid; i < NBUCK; i += 256) lcnt[i] = 0;
        __syncthreads();
        for (int e = e0 + tid; e < e1; e += 256) {
            int d = dst[e];
            int b = d >> 7;
            int r = atomicAdd(&lcnt[b], 1);
            tmp[lbase[b] + r] = ((unsigned)(d & 127) << 17) | (unsigned)src[e];
        }
        return;
    }
    if (bid < NBIN_B + 2) {
        const int w = bid - NBIN_B;
        const float* Wl = w ? W2l : W1l;
        const float* Wr = w ? W2r : W1r;
        unsigned short* wt = w ? w2t : w1t;
        for (int i = tid; i < 64 * 128; i += 256) {
            int c = i >> 7;
            int k = i & 127;
            float v = (k < 64) ? Wl[k * 64 + c] : Wr[(k - 64) * 64 + c];
            wt[c * 128 + k] = bf16bits(v);
        }
        return;
    }
    int i = (bid - NBIN_B - 2) * 256 + tid;
    const int total = N_NODES * DIM / 4;
    if (i >= total) return;
    float4 v = ((const float4*)x)[i];
    ushort4 p;
    p.x = bf16bits(v.x); p.y = bf16bits(v.y); p.z = bf16bits(v.z); p.w = bf16bits(v.w);
    ((ushort4*)xb)[i] = p;
}

// ---------- bucket_sort: per-node sort within each fixed-stride bucket ----------
__global__ __launch_bounds__(256) void bucket_sort_kernel(
    const unsigned* __restrict__ tmp,
    const int* __restrict__ bcnt,
    int* __restrict__ noff,
    int* __restrict__ nend,
    int* __restrict__ ssrc) {
    __shared__ int lcnt[128];
    __shared__ int lofs[128];
    const int tid = threadIdx.x;
    const int b = blockIdx.x;
    const int start = b * CAP;
    const int len = bcnt[b];

    if (tid < 128) lcnt[tid] = 0;
    __syncthreads();
    for (int i = tid; i < len; i += 256)
        atomicAdd(&lcnt[tmp[start + i] >> 17], 1);
    __syncthreads();
    if (tid < 128) lofs[tid] = lcnt[tid];
    __syncthreads();
    for (int ofs = 1; ofs < 128; ofs <<= 1) {
        int v = (tid < 128 && tid >= ofs) ? lofs[tid - ofs] : 0;
        __syncthreads();
        if (tid < 128) lofs[tid] += v;
        __syncthreads();
    }
    if (tid < 128) {
        int inc = lofs[tid];
        int ex = inc - lcnt[tid];
        int n = b * 128 + tid;
        if (n < N_NODES) {
            noff[n] = start + ex;
            nend[n] = start + inc;
        }
        lcnt[tid] = ex;
    }
    __syncthreads();
    for (int i = tid; i < len; i += 256) {
        unsigned v = tmp[start + i];
        int d = v >> 17;
        int r = atomicAdd(&lcnt[d], 1);
        ssrc[start + r] = (int)(v & 0x1FFFFu);
    }
}

// ---------- aggregate (bf16): 4 edges per wave, 16 lanes x uint2 each ----------
__global__ __launch_bounds__(256) void aggregate_bf16_kernel(
    const unsigned short* __restrict__ hb,
    const int* __restrict__ ssrc,
    const int* __restrict__ noff,
    const int* __restrict__ nend,
    unsigned short* __restrict__ meanb) {
    const int lane = threadIdx.x & 63;
    const int wave = (blockIdx.x * blockDim.x + threadIdx.x) >> 6;
    if (wave >= N_NODES) return;
    const int n = wave;
    const int start = noff[n];
    const int end = nend[n];
    const int deg = end - start;
    const int g = lane >> 4;
    const int r = lane & 15;

    float a0 = 0.0f, a1 = 0.0f, a2 = 0.0f, a3 = 0.0f;
    for (int base = start; base < end; base += 64) {
        const int m = min(64, end - base);
        int idx = (lane < m) ? ssrc[base + lane] : 0;
        const int nq = m >> 2;
        int i = 0;
        for (; i + 4 <= nq; i += 4) {
            uint2 v[4];
#pragma unroll
            for (int k = 0; k < 4; ++k) {
                int s = __shfl(idx, 4 * (i + k) + g, 64);
                v[k] = *(const uint2*)(hb + (size_t)s * DIM + r * 4);
            }
#pragma unroll
            for (int k = 0; k < 4; ++k) {
                a0 += bf16raw2f((unsigned short)(v[k].x & 0xFFFFu));
                a1 += bf16raw2f((unsigned short)(v[k].x >> 16));
                a2 += bf16raw2f((unsigned short)(v[k].y & 0xFFFFu));
                a3 += bf16raw2f((unsigned short)(v[k].y >> 16));
            }
        }
        for (; i < nq; ++i) {
            int s = __shfl(idx, 4 * i + g, 64);
            uint2 v = *(const uint2*)(hb + (size_t)s * DIM + r * 4);
            a0 += bf16raw2f((unsigned short)(v.x & 0xFFFFu));
            a1 += bf16raw2f((unsigned short)(v.x >> 16));
            a2 += bf16raw2f((unsigned short)(v.y & 0xFFFFu));
            a3 += bf16raw2f((unsigned short)(v.y >> 16));
        }
        const int tail = m & 3;
        if (tail) {
            const int e0 = nq * 4;
            int s = __shfl(idx, min(e0 + g, m - 1), 64);
            if (g < tail) {
                uint2 v = *(const uint2*)(hb + (size_t)s * DIM + r * 4);
                a0 += bf16raw2f((unsigned short)(v.x & 0xFFFFu));
                a1 += bf16raw2f((unsigned short)(v.x >> 16));
                a2 += bf16raw2f((unsigned short)(v.y & 0xFFFFu));
                a3 += bf16raw2f((unsigned short)(v.y >> 16));
            }
        }
    }
    a0 += __shfl_xor(a0, 16, 64); a0 += __shfl_xor(a0, 32, 64);
    a1 += __shfl_xor(a1, 16, 64); a1 += __shfl_xor(a1, 32, 64);
    a2 += __shfl_xor(a2, 16, 64); a2 += __shfl_xor(a2, 32, 64);
    a3 += __shfl_xor(a3, 16, 64); a3 += __shfl_xor(a3, 32, 64);

    if (g == 0) {
        float inv = 1.0f / fmaxf((float)deg, 1.0f);
        uint2 w;
        w.x = ((unsigned)bf16bits(a1 * inv) << 16) | (unsigned)bf16bits(a0 * inv);
        w.y = ((unsigned)bf16bits(a3 * inv) << 16) | (unsigned)bf16bits(a2 * inv);
        *(uint2*)(meanb + (size_t)n * DIM + r * 4) = w;
    }
}

// ---------- combine via MFMA: out = act([mean|h] @ [Wl;Wr] + b) ----------
// One wave per 16 nodes. A-frag: row = lane&15, k = kblk*32 + (lane>>4)*8 + j.
// B-frag (WT[c][k]): col = lane&15, same k mapping.
// C/D: col = lane&15, row = (lane>>4)*4 + reg   [m89-verified].
template <int LAYER>
__global__ __launch_bounds__(256) void combine_mfma_kernel(
    const unsigned short* __restrict__ meanb,
    const unsigned short* __restrict__ selfb,   // xb (L1) or h1b (L2)
    const unsigned short* __restrict__ WT,      // [64][128] bf16
    const float* __restrict__ bias,
    const float* __restrict__ u1,
    float* __restrict__ outf,                   // L2: final out
    unsigned short* __restrict__ outb) {        // L1: h1b
    const int lane = threadIdx.x & 63;
    const int wid = (blockIdx.x * blockDim.x + threadIdx.x) >> 6;
    const int n0 = wid * 16;
    if (n0 >= N_NODES) return;
    const int rl = lane & 15;
    const int kg = lane >> 4;

    const size_t arow = (size_t)(n0 + rl) * DIM;
    bf16x8 a0 = *(const bf16x8*)(meanb + arow + 0 + kg * 8);
    bf16x8 a1 = *(const bf16x8*)(meanb + arow + 32 + kg * 8);
    bf16x8 a2 = *(const bf16x8*)(selfb + arow + 0 + kg * 8);
    bf16x8 a3 = *(const bf16x8*)(selfb + arow + 32 + kg * 8);

#pragma unroll
    for (int ct = 0; ct < 4; ++ct) {
        const int col = ct * 16 + rl;
        const unsigned short* wcol = WT + (size_t)col * 128 + kg * 8;
        bf16x8 b0 = *(const bf16x8*)(wcol + 0);
        bf16x8 b1 = *(const bf16x8*)(wcol + 32);
        bf16x8 b2 = *(const bf16x8*)(wcol + 64);
        bf16x8 b3 = *(const bf16x8*)(wcol + 96);
        float bv = bias[col];
        f32x4 acc = {bv, bv, bv, bv};
        acc = __builtin_amdgcn_mfma_f32_16x16x32_bf16(a0, b0, acc, 0, 0, 0);
        acc = __builtin_amdgcn_mfma_f32_16x16x32_bf16(a1, b1, acc, 0, 0, 0);
        acc = __builtin_amdgcn_mfma_f32_16x16x32_bf16(a2, b2, acc, 0, 0, 0);
        acc = __builtin_amdgcn_mfma_f32_16x16x32_bf16(a3, b3, acc, 0, 0, 0);

        const int rowb = n0 + kg * 4;
#pragma unroll
        for (int r = 0; r < 4; ++r) {
            float v = fmaxf(acc[r], 0.0f);
            const size_t oidx = (size_t)(rowb + r) * DIM + col;
            if (LAYER == 1) {
                float u = u1[oidx];
                v = (u > 0.5f) ? v * 2.0f : 0.0f;
                outb[oidx] = bf16bits(v);
            } else {
                outf[oidx] = v;
            }
        }
    }
}

extern "C" void kernel_launch(void* const* d_in, const int* in_sizes, int n_in,
                              void* d_out, int out_size, void* d_ws, size_t ws_size,
                              hipStream_t stream) {
    const float* x   = (const float*)d_in[0];
    const int*   ei  = (const int*)d_in[1];
    const float* u1  = (const float*)d_in[2];
    const float* W1l = (const float*)d_in[3];
    const float* W1r = (const float*)d_in[4];
    const float* b1  = (const float*)d_in[5];
    const float* W2l = (const float*)d_in[6];
    const float* W2r = (const float*)d_in[7];
    const float* b2  = (const float*)d_in[8];
    float* out = (float*)d_out;

    const int* src = ei;
    const int* dst = ei + N_EDGES;

    char* ws = (char*)d_ws;
    auto align256 = [](size_t v) { return (v + 255) & ~(size_t)255; };
    size_t o = 0;
    int* noff = (int*)(ws + o); o = align256(o + (size_t)N_NODES * 4);
    int* nend = (int*)(ws + o); o = align256(o + (size_t)N_NODES * 4);
    int* bcnt = (int*)(ws + o); size_t zeroB = (size_t)NBUCK * 4; o = align256(o + zeroB);
    unsigned short* w1t = (unsigned short*)(ws + o); o = align256(o + (size_t)64 * 128 * 2);
    unsigned short* w2t = (unsigned short*)(ws + o); o = align256(o + (size_t)64 * 128 * 2);
    int* ssrc = (int*)(ws + o); o = align256(o + (size_t)NBUCK * CAP * 4);   // 6.4 MB strided
    unsigned short* meanb = (unsigned short*)(ws + o); o = align256(o + (size_t)N_NODES * DIM * 2);
    unsigned* tmp = (unsigned*)meanb;   // aliased: tmp (6.4 MB) consumed before meanb written
    unsigned short* h1b = (unsigned short*)(ws + o); o = align256(o + (size_t)N_NODES * DIM * 2);
    unsigned short* xb  = (unsigned short*)(ws + o); o += (size_t)N_NODES * DIM * 2;
    // total ~46 MB

    hipMemsetAsync(bcnt, 0, zeroB, stream);

    const int cbBlocks = (N_NODES / 16 + 3) / 4;         // 1563 (6250 waves)
    const int aggBlocks = (N_NODES + 3) / 4;             // one wave per node

    bin_prep_kernel<<<NBIN_B + 2 + CVBLKS, 256, 0, stream>>>(
        src, dst, x, W1l, W1r, W2l, W2r, bcnt, tmp, xb, w1t, w2t);
    bucket_sort_kernel<<<NBUCK, 256, 0, stream>>>(tmp, bcnt, noff, nend, ssrc);

    // ---- Layer 1 ----
    aggregate_bf16_kernel<<<aggBlocks, 256, 0, stream>>>(xb, ssrc, noff, nend, meanb);
    combine_mfma_kernel<1><<<cbBlocks, 256, 0, stream>>>(meanb, xb, w1t, b1, u1,
                                                         nullptr, h1b);

    // ---- Layer 2 ----
    aggregate_bf16_kernel<<<aggBlocks, 256, 0, stream>>>(h1b, ssrc, noff, nend, meanb);
    combine_mfma_kernel<2><<<cbBlocks, 256, 0, stream>>>(meanb, h1b, w2t, b2, nullptr,
                                                         out, nullptr);
}